// Round 1
// baseline (96.130 us; speedup 1.0000x reference)
//
#include <hip/hip_runtime.h>

#define NVOX 200000

// ---------------- compaction: ent[j*NVOX + n] = (idx<<5)|k for each present neighbor ----------------
__global__ __launch_bounds__(256) void compact_kernel(const int* __restrict__ nbr,
                                                      int* __restrict__ ent,
                                                      int* __restrict__ cnt) {
    int n = blockIdx.x * 256 + threadIdx.x;
    if (n >= NVOX) return;
    int c = 0;
    #pragma unroll
    for (int k = 0; k < 27; ++k) {
        int idx = nbr[n * 27 + k];
        if (idx >= 0) {
            ent[c * NVOX + n] = (idx << 5) | k;
            ++c;
        }
    }
    cnt[n] = c;
}

// ---------------- layer 0: C=4 -> D=16, relu(conv*s+b) ----------------
__global__ __launch_bounds__(256) void conv0_kernel(const float* __restrict__ feats, // [N,4]
                                                    const int* __restrict__ ent,
                                                    const int* __restrict__ cnt,
                                                    const float* __restrict__ W, // [27,4,16]
                                                    const float* __restrict__ s,
                                                    const float* __restrict__ b,
                                                    float* __restrict__ out) { // [N,16]
    __shared__ float Wl[27 * 68]; // per-k block 64 floats padded to 68 (bank spread, 16B aligned)
    for (int i = threadIdx.x; i < 27 * 64; i += 256)
        Wl[(i >> 6) * 68 + (i & 63)] = W[i];
    __syncthreads();
    int n = blockIdx.x * 256 + threadIdx.x;
    if (n >= NVOX) return;
    float acc[16];
    #pragma unroll
    for (int d = 0; d < 16; ++d) acc[d] = 0.f;
    int c = cnt[n];
    for (int j = 0; j < c; ++j) {
        int e = ent[j * NVOX + n];
        int k = e & 31;
        int idx = e >> 5;
        float4 f = *(const float4*)(feats + idx * 4);
        float g[4] = {f.x, f.y, f.z, f.w};
        const float4* wrow = (const float4*)(Wl + k * 68);
        #pragma unroll
        for (int cc = 0; cc < 4; ++cc) {
            float gc = g[cc];
            float4 w0 = wrow[cc * 4 + 0];
            float4 w1 = wrow[cc * 4 + 1];
            float4 w2 = wrow[cc * 4 + 2];
            float4 w3 = wrow[cc * 4 + 3];
            acc[0]  += gc * w0.x; acc[1]  += gc * w0.y; acc[2]  += gc * w0.z; acc[3]  += gc * w0.w;
            acc[4]  += gc * w1.x; acc[5]  += gc * w1.y; acc[6]  += gc * w1.z; acc[7]  += gc * w1.w;
            acc[8]  += gc * w2.x; acc[9]  += gc * w2.y; acc[10] += gc * w2.z; acc[11] += gc * w2.w;
            acc[12] += gc * w3.x; acc[13] += gc * w3.y; acc[14] += gc * w3.z; acc[15] += gc * w3.w;
        }
    }
    float4* o = (float4*)(out + n * 16);
    float4 r;
    #pragma unroll
    for (int q = 0; q < 4; ++q) {
        float v0 = acc[q * 4 + 0] * s[q * 4 + 0] + b[q * 4 + 0];
        float v1 = acc[q * 4 + 1] * s[q * 4 + 1] + b[q * 4 + 1];
        float v2 = acc[q * 4 + 2] * s[q * 4 + 2] + b[q * 4 + 2];
        float v3 = acc[q * 4 + 3] * s[q * 4 + 3] + b[q * 4 + 3];
        r.x = v0 > 0.f ? v0 : 0.f;
        r.y = v1 > 0.f ? v1 : 0.f;
        r.z = v2 > 0.f ? v2 : 0.f;
        r.w = v3 > 0.f ? v3 : 0.f;
        o[q] = r;
    }
}

// ---------------- generic 16->16 conv body (accumulate) ----------------
__device__ __forceinline__ void conv16_accum(const float* __restrict__ fin,
                                             const int* __restrict__ ent,
                                             int c, int n, const float* Wl,
                                             float acc[16]) {
    for (int j = 0; j < c; ++j) {
        int e = ent[j * NVOX + n];
        int k = e & 31;
        int idx = e >> 5;
        const float4* fp = (const float4*)(fin + idx * 16);
        float4 f0 = fp[0], f1 = fp[1], f2 = fp[2], f3 = fp[3];
        float g[16] = {f0.x, f0.y, f0.z, f0.w, f1.x, f1.y, f1.z, f1.w,
                       f2.x, f2.y, f2.z, f2.w, f3.x, f3.y, f3.z, f3.w};
        const float4* wrow = (const float4*)(Wl + k * 260);
        #pragma unroll
        for (int cc = 0; cc < 16; ++cc) {
            float gc = g[cc];
            float4 w0 = wrow[cc * 4 + 0];
            float4 w1 = wrow[cc * 4 + 1];
            float4 w2 = wrow[cc * 4 + 2];
            float4 w3 = wrow[cc * 4 + 3];
            acc[0]  += gc * w0.x; acc[1]  += gc * w0.y; acc[2]  += gc * w0.z; acc[3]  += gc * w0.w;
            acc[4]  += gc * w1.x; acc[5]  += gc * w1.y; acc[6]  += gc * w1.z; acc[7]  += gc * w1.w;
            acc[8]  += gc * w2.x; acc[9]  += gc * w2.y; acc[10] += gc * w2.z; acc[11] += gc * w2.w;
            acc[12] += gc * w3.x; acc[13] += gc * w3.y; acc[14] += gc * w3.z; acc[15] += gc * w3.w;
        }
    }
}

// ---------------- layer 1: 16->16, relu(conv*s+b) ----------------
__global__ __launch_bounds__(256) void conv1_kernel(const float* __restrict__ fin,
                                                    const int* __restrict__ ent,
                                                    const int* __restrict__ cnt,
                                                    const float* __restrict__ W, // [27,16,16]
                                                    const float* __restrict__ s,
                                                    const float* __restrict__ b,
                                                    float* __restrict__ out) {
    __shared__ float Wl[27 * 260]; // 256-float blocks padded to 260 (k*260 %32 = k*4 -> 8 bank groups)
    for (int i = threadIdx.x; i < 27 * 256; i += 256)
        Wl[(i >> 8) * 260 + (i & 255)] = W[i];
    __syncthreads();
    int n = blockIdx.x * 256 + threadIdx.x;
    if (n >= NVOX) return;
    float acc[16];
    #pragma unroll
    for (int d = 0; d < 16; ++d) acc[d] = 0.f;
    int c = cnt[n];
    conv16_accum(fin, ent, c, n, Wl, acc);
    float4* o = (float4*)(out + n * 16);
    #pragma unroll
    for (int q = 0; q < 4; ++q) {
        float4 r;
        float v0 = acc[q * 4 + 0] * s[q * 4 + 0] + b[q * 4 + 0];
        float v1 = acc[q * 4 + 1] * s[q * 4 + 1] + b[q * 4 + 1];
        float v2 = acc[q * 4 + 2] * s[q * 4 + 2] + b[q * 4 + 2];
        float v3 = acc[q * 4 + 3] * s[q * 4 + 3] + b[q * 4 + 3];
        r.x = v0 > 0.f ? v0 : 0.f;
        r.y = v1 > 0.f ? v1 : 0.f;
        r.z = v2 > 0.f ? v2 : 0.f;
        r.w = v3 > 0.f ? v3 : 0.f;
        o[q] = r;
    }
}

// ---------------- layer 2 + residual + relu + final 16->3 linear ----------------
__global__ __launch_bounds__(256) void conv2_final_kernel(const float* __restrict__ fin, // h [N,16]
                                                          const int* __restrict__ ent,
                                                          const int* __restrict__ cnt,
                                                          const float* __restrict__ W, // [27,16,16]
                                                          const float* __restrict__ s,
                                                          const float* __restrict__ b,
                                                          const float* __restrict__ idn, // x [N,16]
                                                          const float* __restrict__ Wlin, // [16,3]
                                                          const float* __restrict__ blin, // [3]
                                                          float* __restrict__ out) { // [N,3]
    __shared__ float Wl[27 * 260];
    for (int i = threadIdx.x; i < 27 * 256; i += 256)
        Wl[(i >> 8) * 260 + (i & 255)] = W[i];
    __syncthreads();
    int n = blockIdx.x * 256 + threadIdx.x;
    if (n >= NVOX) return;
    float acc[16];
    #pragma unroll
    for (int d = 0; d < 16; ++d) acc[d] = 0.f;
    int c = cnt[n];
    conv16_accum(fin, ent, c, n, Wl, acc);
    const float4* ip = (const float4*)(idn + n * 16);
    float4 i0 = ip[0], i1 = ip[1], i2 = ip[2], i3 = ip[3];
    float id[16] = {i0.x, i0.y, i0.z, i0.w, i1.x, i1.y, i1.z, i1.w,
                    i2.x, i2.y, i2.z, i2.w, i3.x, i3.y, i3.z, i3.w};
    float o0 = blin[0], o1 = blin[1], o2 = blin[2];
    #pragma unroll
    for (int d = 0; d < 16; ++d) {
        float v = acc[d] * s[d] + b[d] + id[d];
        v = v > 0.f ? v : 0.f;
        o0 += v * Wlin[d * 3 + 0];
        o1 += v * Wlin[d * 3 + 1];
        o2 += v * Wlin[d * 3 + 2];
    }
    out[n * 3 + 0] = o0;
    out[n * 3 + 1] = o1;
    out[n * 3 + 2] = o2;
}

extern "C" void kernel_launch(void* const* d_in, const int* in_sizes, int n_in,
                              void* d_out, int out_size, void* d_ws, size_t ws_size,
                              hipStream_t stream) {
    const float* feats = (const float*)d_in[0];
    const int*   nbr   = (const int*)d_in[1];
    const float* W0    = (const float*)d_in[2];
    const float* s0    = (const float*)d_in[3];
    const float* b0    = (const float*)d_in[4];
    const float* W1    = (const float*)d_in[5];
    const float* s1    = (const float*)d_in[6];
    const float* b1    = (const float*)d_in[7];
    const float* W2    = (const float*)d_in[8];
    const float* s2    = (const float*)d_in[9];
    const float* b2    = (const float*)d_in[10];
    const float* Wlin  = (const float*)d_in[11];
    const float* blin  = (const float*)d_in[12];
    float* out = (float*)d_out;

    char* ws = (char*)d_ws;
    int*   ent = (int*)ws;                       // 27*N*4  = 21,600,000 B
    int*   cnt = (int*)(ws + 21600000);          //  N*4    =    800,000 B
    float* x   = (float*)(ws + 22400000);        // 16*N*4  = 12,800,000 B
    float* h   = (float*)(ws + 35200000);        // 16*N*4  = 12,800,000 B

    int blocks = (NVOX + 255) / 256;
    compact_kernel<<<blocks, 256, 0, stream>>>(nbr, ent, cnt);
    conv0_kernel<<<blocks, 256, 0, stream>>>(feats, ent, cnt, W0, s0, b0, x);
    conv1_kernel<<<blocks, 256, 0, stream>>>(x, ent, cnt, W1, s1, b1, h);
    conv2_final_kernel<<<blocks, 256, 0, stream>>>(h, ent, cnt, W2, s2, b2, x, Wlin, blin, out);
}